// Round 8
// baseline (131.760 us; speedup 1.0000x reference)
//
#include <hip/hip_runtime.h>
#include <math.h>

#define NN   512
#define CH   32      // receivers per chunk
#define NCHH 8       // chunks per half-block (2 blocks per sender)

#define C1 0.06154574548966636f   // 1/sqrt(264)
#define C2 0.08838834764831845f   // 1/sqrt(128)
#define SQRT3 1.7320508075688772f

typedef __attribute__((ext_vector_type(8))) short bf16x8;   // 8 bf16 = 4 VGPRs
typedef __attribute__((ext_vector_type(4))) float f32x4;

#define MFMA16 __builtin_amdgcn_mfma_f32_16x16x32_bf16
#define CVT_PK(dst, a, b) asm("v_cvt_pk_bf16_f32 %0, %1, %2" : "=v"(dst) : "v"(a), "v"(b))

__device__ __forceinline__ float silu_f(float x) {
    float e = __builtin_amdgcn_exp2f(x * -1.442695041f);
    return x * __builtin_amdgcn_rcpf(1.0f + e);
}
__device__ __forceinline__ float sigm_f(float x) {
    float e = __builtin_amdgcn_exp2f(x * -1.442695041f);
    return __builtin_amdgcn_rcpf(1.0f + e);
}
__device__ __forceinline__ short f2bf(float f) {
    unsigned u = __builtin_bit_cast(unsigned, f);
    u = (u + 0x7FFFu + ((u >> 16) & 1u)) >> 16;
    return (short)u;
}

// ---------------------------------------------------------------------------
// k_packall: all packing + proj in ONE launch. Weights PRE-SCALED by their
// layer constant so k_edge epilogues are pure silu.
// Frag (ct,kt), lane l, elem j holds W[32kt + (l>>4)*8 + j][16ct + (l&15)].
// ---------------------------------------------------------------------------
__device__ __forceinline__ void packW(const float* __restrict__ W,
                                      short* __restrict__ out, int ncols, int ct,
                                      float scale)
{
    int t = threadIdx.x;
    int lane = t & 63, kt = (t >> 6) & 3;
    int g = lane >> 4, c = lane & 15;
    bf16x8 v;
    #pragma unroll
    for (int j = 0; j < 8; ++j)
        v[j] = f2bf(W[(kt * 32 + g * 8 + j) * ncols + ct * 16 + c] * scale);
    *(bf16x8*)(out + (size_t)(ct * 256 + t) * 8) = v;
}

__global__ __launch_bounds__(256)
void k_packall(const float* __restrict__ We2, const float* __restrict__ Wx1,
               const float* __restrict__ Wx2, const float* __restrict__ Wtp,
               const float* __restrict__ We1, const float* __restrict__ Winf,
               const float* __restrict__ feat,
               short* __restrict__ We2p, short* __restrict__ Wx1p,
               short* __restrict__ Wx2p, short* __restrict__ Wtpp,
               short* __restrict__ We1Lp, short* __restrict__ BWinfp,
               float* __restrict__ FsP, float* __restrict__ FrP)
{
    const int b = blockIdx.x, t = threadIdx.x;
    if (b < 8)  { packW(We2, We2p, 128, b,      C2);       return; }
    if (b < 16) { packW(Wx1, Wx1p, 128, b - 8,  C2);       return; }
    if (b < 24) { packW(Wx2, Wx2p, 128, b - 16, C2);       return; }
    if (b < 28) { packW(Wtp, Wtpp,  64, b - 24, 0.03125f); return; } // 1/sqrt(U*V)=1/32
    if (b == 28) {
        // We1 length rows (k<8), K padded to 32, pre-scaled C1
        #pragma unroll
        for (int h = 0; h < 2; ++h) {
            int tt = t + h * 256;
            int ct = tt >> 6, l = tt & 63, g = l >> 4, c = l & 15;
            bf16x8 v = {0,0,0,0,0,0,0,0};
            if (g == 0) {
                #pragma unroll
                for (int j = 0; j < 8; ++j)
                    v[j] = f2bf(We1[j * 128 + ct * 16 + c] * C1);
            }
            *(bf16x8*)(We1Lp + (size_t)tt * 8) = v;
        }
        // Winf as column-REPLICATED B-frag (every col = Winf), pre-scaled C2:
        // e-dot MFMA gives every lane the dot for its own D rows.
        {
            int kt = t >> 6, l = t & 63, g = l >> 4;
            bf16x8 v;
            #pragma unroll
            for (int j = 0; j < 8; ++j)
                v[j] = f2bf(Winf[kt * 32 + g * 8 + j] * C2);
            *(bf16x8*)(BWinfp + (size_t)t * 8) = v;
        }
        return;
    }
    // ---- proj: 2 nodes per block, outputs pre-scaled by C1 ----
    __shared__ float sF[256];
    const int n = (b - 29) * 2 + (t >> 7), j = t & 127, hb = t & 128;
    sF[t] = feat[n * 128 + j];
    __syncthreads();
    float a = 0.f, bb = 0.f;
    #pragma unroll 8
    for (int k = 0; k < 128; ++k) {
        float f = sF[hb + k];
        a  = fmaf(f, We1[(8   + k) * 128 + j], a);
        bb = fmaf(f, We1[(136 + k) * 128 + j], bb);
    }
    FsP[n * 128 + j] = a * C1;
    FrP[n * 128 + j] = bb * C1;
}

// ---------------------------------------------------------------------------
// laundered B-fragment loader (anchors loads at the call site)
// ---------------------------------------------------------------------------
__device__ __forceinline__ void loadBz(const short* __restrict__ p,
                                       bf16x8 (&B)[2][4], int w, int lane)
{
    int zz = 0; asm volatile("" : "+v"(zz));
    const bf16x8* p8 = (const bf16x8*)p;
    #pragma unroll
    for (int ctl = 0; ctl < 2; ++ctl)
        #pragma unroll
        for (int kt = 0; kt < 4; ++kt)
            B[ctl][kt] = p8[((w * 2 + ctl) * 4 + kt) * 64 + lane + zz];
}

// MFMA-only 32x128 @ 128x128 layer (weights pre-scaled)
__device__ __forceinline__ void gemm_mfma(const short* sIn_, const bf16x8 (&B)[2][4],
                                          const int (&adrK)[4], f32x4 (&acc)[2][2])
{
    const char* sIn = (const char*)sIn_;
    const f32x4 z = {0.f, 0.f, 0.f, 0.f};
    acc[0][0] = z; acc[0][1] = z; acc[1][0] = z; acc[1][1] = z;
    __builtin_amdgcn_s_setprio(1);
    #pragma unroll
    for (int kt = 0; kt < 4; ++kt) {
        bf16x8 a0 = *(const bf16x8*)(sIn + adrK[kt]);
        bf16x8 a1 = *(const bf16x8*)(sIn + adrK[kt] + 4096);
        acc[0][0] = MFMA16(a0, B[0][kt], acc[0][0], 0, 0, 0);
        acc[0][1] = MFMA16(a0, B[1][kt], acc[0][1], 0, 0, 0);
        acc[1][0] = MFMA16(a1, B[0][kt], acc[1][0], 0, 0, 0);
        acc[1][1] = MFMA16(a1, B[1][kt], acc[1][1], 0, 0, 0);
    }
    __builtin_amdgcn_s_setprio(0);
}

// epilogue: pure silu -> bf16 scatter into LDS (optionally keep fp32)
template<bool KEEP>
__device__ __forceinline__ void epi_store(const f32x4 (&acc)[2][2], short* sOut_,
                                          const int (&wAdr)[2][4], f32x4 (&keep)[2][2])
{
    char* sOut = (char*)sOut_;
    #pragma unroll
    for (int rt = 0; rt < 2; ++rt)
        #pragma unroll
        for (int ctl = 0; ctl < 2; ++ctl) {
            float v0 = silu_f(acc[rt][ctl][0]);
            float v1 = silu_f(acc[rt][ctl][1]);
            float v2 = silu_f(acc[rt][ctl][2]);
            float v3 = silu_f(acc[rt][ctl][3]);
            if (KEEP) {
                keep[rt][ctl][0] = v0; keep[rt][ctl][1] = v1;
                keep[rt][ctl][2] = v2; keep[rt][ctl][3] = v3;
            }
            unsigned p01, p23;
            CVT_PK(p01, v0, v1);
            CVT_PK(p23, v2, v3);
            char* o = sOut + rt * 4096;
            *(short*)(o + wAdr[ctl][0]) = (short)(p01 & 0xFFFFu);
            *(short*)(o + wAdr[ctl][1]) = (short)(p01 >> 16);
            *(short*)(o + wAdr[ctl][2]) = (short)(p23 & 0xFFFFu);
            *(short*)(o + wAdr[ctl][3]) = (short)(p23 >> 16);
        }
}

// ---------------------------------------------------------------------------
// k_edge: one block per (sender, half); 8 chunks of 32 receivers.
// 4 barriers/chunk: wave-private sLS kills B1/B7; Winf-MFMA kills B4.
// ---------------------------------------------------------------------------
__global__ __launch_bounds__(256, 4)
void k_edge(const float* __restrict__ pos,
            const float* __restrict__ FsP,
            const float* __restrict__ FrP,
            const short* __restrict__ We1Lp,
            const short* __restrict__ We2p,
            const short* __restrict__ Wx1p,
            const short* __restrict__ Wx2p,
            const short* __restrict__ Wtpp,
            const short* __restrict__ BWinfp,
            float* __restrict__ MI2,
            float* __restrict__ VEC2)
{
    __shared__ __align__(16) short sX[CH * 128];     // activations ping (swizzled)
    __shared__ __align__(16) short sY[CH * 128];     // activations pong
    __shared__ __align__(16) float sLS[4 * 1024];    // per-WAVE (sh.xyz,len), v-swizzled
    __shared__ float sPosS[24];
    __shared__ float sVp[4 * 24];

    const int bid = blockIdx.x;
    const int s = bid >> 1, half = bid & 1;
    const int t = threadIdx.x;
    const int lane = t & 63, w = t >> 6;
    const int rl = lane & 15, kg = lane >> 4;

    // ---- per-thread constant LDS byte addresses ----
    const int swz = (rl & 7) << 4;
    const int ktperm = (rl & 4) << 4;
    const int baseRd = rl * 256 + ((kg * 16) ^ (swz & 0x30));
    int adrK[4];
    #pragma unroll
    for (int kt = 0; kt < 4; ++kt) adrK[kt] = baseRd + ((kt * 64) ^ ktperm);
    int wAdr[2][4];
    #pragma unroll
    for (int ctl = 0; ctl < 2; ++ctl)
        #pragma unroll
        for (int jj = 0; jj < 4; ++jj) {
            int r = kg * 4 + jj;
            wAdr[ctl][jj] = r * 256 + ((w * 64 + ctl * 32 + 2 * rl) ^ ((r & 7) << 4));
        }
    const int colg0 = w * 32 + rl, colg1 = colg0 + 16;
    const int vv = w * 2 + (rl >> 3);
    float* myLS = sLS + w * 1024;

    if (t < 24) sPosS[t] = pos[s * 24 + t];

    const float fs0 = FsP[s * 128 + colg0];   // pre-scaled C1
    const float fs1 = FsP[s * 128 + colg1];

    // pinned: replicated-Winf B-frags (e-dot on the idle MFMA pipe)
    bf16x8 BW[4];
    {
        const bf16x8* p8 = (const bf16x8*)BWinfp;
        #pragma unroll
        for (int kt = 0; kt < 4; ++kt) BW[kt] = p8[kt * 64 + lane];
    }

    float miacc0 = 0.f, miacc1 = 0.f;
    float vax = 0.f, vay = 0.f, vaz = 0.f;
    const f32x4 z4 = {0.f, 0.f, 0.f, 0.f};
    __syncthreads();                                              // B0 (init only)

    for (int c = 0; c < NCHH; ++c) {
        const int r0 = (half * NCHH + c) * CH;

        // ==== chunk-top issue: We2 frags + We1L frags + FrP->C-operand ====
        bf16x8 Bw[2][4];
        loadBz(We2p, Bw, w, lane);
        bf16x8 bL0, bL1;
        {
            int zz = 0; asm volatile("" : "+v"(zz));
            const bf16x8* pL = (const bf16x8*)We1Lp;
            bL0 = pL[(w * 2 + 0) * 64 + lane + zz];
            bL1 = pL[(w * 2 + 1) * 64 + lane + zz];
        }
        f32x4 cIn[2][2];
        {
            int zz = 0; asm volatile("" : "+v"(zz));
            #pragma unroll
            for (int rt = 0; rt < 2; ++rt)
                #pragma unroll
                for (int jj = 0; jj < 4; ++jj) {
                    const float* fp = FrP + (size_t)(r0 + rt * 16 + kg * 4 + jj) * 128 + zz;
                    cIn[rt][0][jj] = fp[colg0] + fs0;   // acc-init = fr' + fs'
                    cIn[rt][1][jj] = fp[colg1] + fs1;
                }
        }

        // ---- ph0: lengths + sh1 -> WAVE-PRIVATE sLS (no barrier needed) ----
        {
            int r = lane & 31, vb = lane >> 5;        // 1 row, 4 v's per lane
            const float* pp = pos + (size_t)(r0 + r) * 24 + vb * 12;
            float4 q0 = *(const float4*)pp;
            float4 q1 = *(const float4*)(pp + 4);
            float4 q2 = *(const float4*)(pp + 8);
            const float* sp = sPosS + vb * 12;
            float4 s0 = *(const float4*)sp;
            float4 s1 = *(const float4*)(sp + 4);
            float4 s2 = *(const float4*)(sp + 8);
            float prx[4] = {q0.x, q0.w, q1.z, q2.y};
            float pry[4] = {q0.y, q1.x, q1.w, q2.z};
            float prz[4] = {q0.z, q1.y, q2.x, q2.w};
            float ssx[4] = {s0.x, s0.w, s1.z, s2.y};
            float ssy[4] = {s0.y, s1.x, s1.w, s2.z};
            float ssz[4] = {s0.z, s1.y, s2.x, s2.w};
            #pragma unroll
            for (int i = 0; i < 4; ++i) {
                float dx = ssx[i] - prx[i];
                float dy = ssy[i] - pry[i];
                float dz = ssz[i] - prz[i];
                float sq = fmaxf(dx*dx + dy*dy + dz*dz, 1e-20f);
                float rs = __builtin_amdgcn_rsqf(sq);
                float len = sq * rs;                   // = sqrt(sq)
                float inv = SQRT3 * rs;
                f32x4 o; o[0] = dx*inv; o[1] = dy*inv; o[2] = dz*inv; o[3] = len;
                int v = vb * 4 + i;
                *(f32x4*)(myLS + (r * 8 + (v ^ (r & 7))) * 4) = o;
            }
        }

        // ---- L1: lens @ We1L' with C-operand = fr'+fs'; pure-silu epi -> sX ----
        {
            bf16x8 aL0 = {0,0,0,0,0,0,0,0}, aL1 = {0,0,0,0,0,0,0,0};
            if (kg == 0) {
                const float* Lp = myLS + rl * 32;
                const float* Lq = myLS + (rl + 16) * 32;
                unsigned u0[4], u1[4];
                #pragma unroll
                for (int jp = 0; jp < 4; ++jp) {
                    CVT_PK(u0[jp], Lp[((2*jp)   ^ (rl & 7)) * 4 + 3],
                                   Lp[((2*jp+1) ^ (rl & 7)) * 4 + 3]);
                    CVT_PK(u1[jp], Lq[((2*jp)   ^ (rl & 7)) * 4 + 3],
                                   Lq[((2*jp+1) ^ (rl & 7)) * 4 + 3]);
                }
                uint4 v0 = {u0[0], u0[1], u0[2], u0[3]};
                uint4 v1 = {u1[0], u1[1], u1[2], u1[3]};
                aL0 = __builtin_bit_cast(bf16x8, v0);
                aL1 = __builtin_bit_cast(bf16x8, v1);
            }
            f32x4 aP[2][2];
            aP[0][0] = MFMA16(aL0, bL0, cIn[0][0], 0, 0, 0);
            aP[0][1] = MFMA16(aL0, bL1, cIn[0][1], 0, 0, 0);
            aP[1][0] = MFMA16(aL1, bL0, cIn[1][0], 0, 0, 0);
            aP[1][1] = MFMA16(aL1, bL1, cIn[1][1], 0, 0, 0);
            f32x4 dummy[2][2];
            epi_store<false>(aP, sX, wAdr, dummy);
        }
        __syncthreads();                                          // B1

        // ---- L2: m = silu(a1 @ We2') -> sY ; keep fp32 ----
        f32x4 acc[2][2], keepM[2][2];
        gemm_mfma(sX, Bw, adrK, acc);
        bf16x8 Bn[2][4];
        loadBz(Wx1p, Bn, w, lane);          // Wx1 in flight across epi+barrier
        epi_store<true>(acc, sY, wAdr, keepM);
        __syncthreads();                                          // B2

        // ---- L3: phi1 = silu(m @ Wx1') + e-dot MFMAs (replicated Winf) ----
        f32x4 eacc0 = z4, eacc1 = z4;
        {
            const char* sYc = (const char*)sY;
            const f32x4 z = z4;
            acc[0][0] = z; acc[0][1] = z; acc[1][0] = z; acc[1][1] = z;
            __builtin_amdgcn_s_setprio(1);
            #pragma unroll
            for (int kt = 0; kt < 4; ++kt) {
                bf16x8 a0 = *(const bf16x8*)(sYc + adrK[kt]);
                bf16x8 a1 = *(const bf16x8*)(sYc + adrK[kt] + 4096);
                acc[0][0] = MFMA16(a0, Bn[0][kt], acc[0][0], 0, 0, 0);
                acc[0][1] = MFMA16(a0, Bn[1][kt], acc[0][1], 0, 0, 0);
                acc[1][0] = MFMA16(a1, Bn[0][kt], acc[1][0], 0, 0, 0);
                acc[1][1] = MFMA16(a1, Bn[1][kt], acc[1][1], 0, 0, 0);
                eacc0 = MFMA16(a0, BW[kt], eacc0, 0, 0, 0);
                eacc1 = MFMA16(a1, BW[kt], eacc1, 0, 0, 0);
            }
            __builtin_amdgcn_s_setprio(0);
        }
        // ---- e (in-register, rows match this thread's D rows) + mi acc ----
        {
            const int sl = s - r0;
            #pragma unroll
            for (int jj = 0; jj < 4; ++jj) {
                int row = kg * 4 + jj;
                float e0 = (row == sl)      ? 0.f : sigm_f(eacc0[jj]);
                float e1 = (row + 16 == sl) ? 0.f : sigm_f(eacc1[jj]);
                miacc0 = fmaf(keepM[0][0][jj], e0, fmaf(keepM[1][0][jj], e1, miacc0));
                miacc1 = fmaf(keepM[0][1][jj], e0, fmaf(keepM[1][1][jj], e1, miacc1));
            }
        }
        loadBz(Wx2p, Bw, w, lane);          // Wx2 in flight across epi+barrier
        epi_store<false>(acc, sX, wAdr, keepM);
        __syncthreads();                                          // B3

        // ---- L4: phi2 = silu(phi1 @ Wx2') -> sY ; Wtp issued under epi ----
        gemm_mfma(sX, Bw, adrK, acc);
        bf16x8 Bt[4];
        {
            int zz = 0; asm volatile("" : "+v"(zz));
            const bf16x8* p8 = (const bf16x8*)Wtpp;
            #pragma unroll
            for (int kt = 0; kt < 4; ++kt) Bt[kt] = p8[(w * 4 + kt) * 64 + lane + zz];
        }
        epi_store<false>(acc, sY, wAdr, keepM);
        __syncthreads();                                          // B4

        // ---- TP gemm (Wtp' includes 1/32) + vec acc from own sLS ----
        {
            f32x4 acc0 = z4, acc1 = z4;
            const char* sYc = (const char*)sY;
            __builtin_amdgcn_s_setprio(1);
            #pragma unroll
            for (int kt = 0; kt < 4; ++kt) {
                bf16x8 a0 = *(const bf16x8*)(sYc + adrK[kt]);
                bf16x8 a1 = *(const bf16x8*)(sYc + adrK[kt] + 4096);
                acc0 = MFMA16(a0, Bt[kt], acc0, 0, 0, 0);
                acc1 = MFMA16(a1, Bt[kt], acc1, 0, 0, 0);
            }
            __builtin_amdgcn_s_setprio(0);
            #pragma unroll
            for (int rt = 0; rt < 2; ++rt)
                #pragma unroll
                for (int jj = 0; jj < 4; ++jj) {
                    int row = rt * 16 + kg * 4 + jj;
                    const f32x4 sh = *(const f32x4*)(myLS + (row * 8 + (vv ^ (row & 7))) * 4);
                    float g = rt ? acc1[jj] : acc0[jj];
                    vax = fmaf(g, sh[0], vax);
                    vay = fmaf(g, sh[1], vay);
                    vaz = fmaf(g, sh[2], vaz);
                }
        }
        // no barrier: sLS is wave-private; sX(c+1) writes are post-B4
    }

    // ---- epilogue: m_i reduce over row-groups ----
    miacc0 += __shfl_xor(miacc0, 16); miacc0 += __shfl_xor(miacc0, 32);
    miacc1 += __shfl_xor(miacc1, 16); miacc1 += __shfl_xor(miacc1, 32);
    if (lane < 16) {
        float* mo = MI2 + (size_t)(half * NN + s) * 128;
        mo[w * 32 + lane]      = miacc0;
        mo[w * 32 + 16 + lane] = miacc1;
    }
    // ---- vec reduce (1/32 already folded into Wtpp) ----
    vax += __shfl_xor(vax, 8);  vay += __shfl_xor(vay, 8);  vaz += __shfl_xor(vaz, 8);
    vax += __shfl_xor(vax, 16); vay += __shfl_xor(vay, 16); vaz += __shfl_xor(vaz, 16);
    vax += __shfl_xor(vax, 32); vay += __shfl_xor(vay, 32); vaz += __shfl_xor(vaz, 32);
    if ((lane & 56) == 0) {
        float* vp = sVp + w * 24 + lane * 3;
        vp[0] = vax; vp[1] = vay; vp[2] = vaz;
    }
    __syncthreads();
    if (t < 24) {
        float sum = sVp[t] + sVp[24 + t] + sVp[48 + t] + sVp[72 + t];
        VEC2[(size_t)(half * NN + s) * 24 + t] = sum;
    }
}

// ---------------------------------------------------------------------------
// k_node: per-node h-MLP + residual + position update (sums the 2 halves).
// ---------------------------------------------------------------------------
__global__ __launch_bounds__(128)
void k_node(const float* __restrict__ pos, const float* __restrict__ feat,
            const float* __restrict__ Wh1, const float* __restrict__ Wh2,
            const float* __restrict__ Wh3,
            const float* __restrict__ MI2, const float* __restrict__ VEC2,
            float* __restrict__ outPos, float* __restrict__ outFeat)
{
    __shared__ float sMi[128], sF[128], sH[128];
    int n = blockIdx.x, j = threadIdx.x;
    sMi[j] = MI2[n * 128 + j] + MI2[NN * 128 + n * 128 + j];
    sF[j]  = feat[n * 128 + j];
    __syncthreads();
    float a = 0.f;
    #pragma unroll 8
    for (int k = 0; k < 128; ++k) a = fmaf(sMi[k], Wh1[k * 128 + j], a);
    #pragma unroll 8
    for (int k = 0; k < 128; ++k) a = fmaf(sF[k], Wh1[(128 + k) * 128 + j], a);
    a = silu_f(a * 0.0625f);            // 1/sqrt(256)
    sH[j] = a;
    __syncthreads();
    float b = 0.f;
    #pragma unroll 8
    for (int k = 0; k < 128; ++k) b = fmaf(sH[k], Wh2[k * 128 + j], b);
    b = silu_f(b * C2);
    sMi[j] = b;
    __syncthreads();
    float cc = 0.f;
    #pragma unroll 8
    for (int k = 0; k < 128; ++k) cc = fmaf(sMi[k], Wh3[k * 128 + j], cc);
    outFeat[n * 128 + j] = cc * C2 + sF[j];
    if (j < 24) outPos[n * 24 + j] = pos[n * 24 + j]
                                   + VEC2[n * 24 + j] + VEC2[NN * 24 + n * 24 + j];
}

// ---------------------------------------------------------------------------
extern "C" void kernel_launch(void* const* d_in, const int* in_sizes, int n_in,
                              void* d_out, int out_size, void* d_ws, size_t ws_size,
                              hipStream_t stream) {
    const float* pos  = (const float*)d_in[0];
    const float* feat = (const float*)d_in[1];
    const float* We1  = (const float*)d_in[2];
    const float* We2  = (const float*)d_in[3];
    const float* Wx1  = (const float*)d_in[4];
    const float* Wx2  = (const float*)d_in[5];
    const float* Winf = (const float*)d_in[6];
    const float* Wtp  = (const float*)d_in[7];
    const float* Wh1  = (const float*)d_in[8];
    const float* Wh2  = (const float*)d_in[9];
    const float* Wh3  = (const float*)d_in[10];

    float* outPos  = (float*)d_out;              // [512*8*3]
    float* outFeat = (float*)d_out + NN * 24;    // [512*128]

    float* ws   = (float*)d_ws;
    float* FsP  = ws;                   // 65536 floats (pre-scaled C1)
    float* FrP  = ws + 65536;           // 65536 (pre-scaled C1)
    float* MI2  = ws + 131072;          // 2*65536
    float* VEC2 = ws + 262144;          // 2*12288
    short* wpack  = (short*)(ws + 286720);
    short* We2p   = wpack;              // 16384 shorts
    short* Wx1p   = wpack + 16384;      // 16384
    short* Wx2p   = wpack + 32768;      // 16384
    short* Wtpp   = wpack + 49152;      // 8192
    short* We1Lp  = wpack + 57344;      // 4096
    short* BWinfp = wpack + 61440;      // 2048   (total ws ~1.26 MB)

    k_packall<<<dim3(285), dim3(256), 0, stream>>>(We2, Wx1, Wx2, Wtp, We1, Winf, feat,
                                                   We2p, Wx1p, Wx2p, Wtpp, We1Lp,
                                                   BWinfp, FsP, FrP);
    k_edge<<<dim3(2 * NN), dim3(256), 0, stream>>>(pos, FsP, FrP, We1Lp,
                                                   We2p, Wx1p, Wx2p, Wtpp, BWinfp,
                                                   MI2, VEC2);
    k_node<<<dim3(NN), dim3(128), 0, stream>>>(pos, feat, Wh1, Wh2, Wh3, MI2, VEC2,
                                               outPos, outFeat);
}

// Round 9
// 94.967 us; speedup vs baseline: 1.3874x; 1.3874x over previous
//
#include <hip/hip_runtime.h>
#include <math.h>

#define NN   512
#define NV   8
#define CH   32      // receivers per chunk
#define NCHH 8       // chunks per half-block (2 blocks per sender)

#define C1 0.06154574548966636f   // 1/sqrt(264)
#define C2 0.08838834764831845f   // 1/sqrt(128)
#define SQRT3 1.7320508075688772f

typedef __attribute__((ext_vector_type(8))) short bf16x8;   // 8 bf16 = 4 VGPRs
typedef __attribute__((ext_vector_type(4))) float f32x4;

#define MFMA16 __builtin_amdgcn_mfma_f32_16x16x32_bf16
#define CVT_PK(dst, a, b) asm("v_cvt_pk_bf16_f32 %0, %1, %2" : "=v"(dst) : "v"(a), "v"(b))

__device__ __forceinline__ float silu_f(float x) {
    float e = __builtin_amdgcn_exp2f(x * -1.442695041f);
    return x * __builtin_amdgcn_rcpf(1.0f + e);
}
__device__ __forceinline__ float sigm_f(float x) {
    float e = __builtin_amdgcn_exp2f(x * -1.442695041f);
    return __builtin_amdgcn_rcpf(1.0f + e);
}
__device__ __forceinline__ short f2bf(float f) {
    unsigned u = __builtin_bit_cast(unsigned, f);
    u = (u + 0x7FFFu + ((u >> 16) & 1u)) >> 16;
    return (short)u;
}
__device__ __forceinline__ float bfhi(unsigned u) {
    return __builtin_bit_cast(float, u & 0xFFFF0000u);
}
__device__ __forceinline__ float bflo(unsigned u) {
    return __builtin_bit_cast(float, u << 16);
}

// ---------------------------------------------------------------------------
// k_packall: all weight packing + proj in ONE launch; weights PRE-SCALED.
// Frag (ct,kt), lane l, elem j holds W[32kt + (l>>4)*8 + j][16ct + (l&15)].
// ---------------------------------------------------------------------------
__device__ __forceinline__ void packW(const float* __restrict__ W,
                                      short* __restrict__ out, int ncols, int ct,
                                      float scale)
{
    int t = threadIdx.x;
    int lane = t & 63, kt = (t >> 6) & 3;
    int g = lane >> 4, c = lane & 15;
    bf16x8 v;
    #pragma unroll
    for (int j = 0; j < 8; ++j)
        v[j] = f2bf(W[(kt * 32 + g * 8 + j) * ncols + ct * 16 + c] * scale);
    *(bf16x8*)(out + (size_t)(ct * 256 + t) * 8) = v;
}

__global__ __launch_bounds__(256)
void k_packall(const float* __restrict__ We2, const float* __restrict__ Wx1,
               const float* __restrict__ Wx2, const float* __restrict__ Wtp,
               const float* __restrict__ We1, const float* __restrict__ feat,
               short* __restrict__ We2p, short* __restrict__ Wx1p,
               short* __restrict__ Wx2p, short* __restrict__ Wtpp,
               short* __restrict__ We1Lp,
               float* __restrict__ FsP, float* __restrict__ FrP)
{
    const int b = blockIdx.x, t = threadIdx.x;
    if (b < 8)  { packW(We2, We2p, 128, b,      C2);       return; }
    if (b < 16) { packW(Wx1, Wx1p, 128, b - 8,  C2);       return; }
    if (b < 24) { packW(Wx2, Wx2p, 128, b - 16, C2);       return; }
    if (b < 28) { packW(Wtp, Wtpp,  64, b - 24, 0.03125f); return; } // 1/sqrt(U*V)
    if (b == 28) {
        // B-frags of We1 rows 0..7, K padded to 32, pre-scaled C1.
        #pragma unroll
        for (int h = 0; h < 2; ++h) {
            int tt = t + h * 256;
            int ct = tt >> 6, l = tt & 63, g = l >> 4, c = l & 15;
            bf16x8 v = {0,0,0,0,0,0,0,0};
            if (g == 0) {
                #pragma unroll
                for (int j = 0; j < 8; ++j)
                    v[j] = f2bf(We1[j * 128 + ct * 16 + c] * C1);
            }
            *(bf16x8*)(We1Lp + (size_t)tt * 8) = v;
        }
        return;
    }
    // ---- proj: 2 nodes per block, outputs pre-scaled by C1 ----
    __shared__ float sF[256];
    const int n = (b - 29) * 2 + (t >> 7), j = t & 127, hb = t & 128;
    sF[t] = feat[n * 128 + j];
    __syncthreads();
    float a = 0.f, bb = 0.f;
    #pragma unroll 8
    for (int k = 0; k < 128; ++k) {
        float f = sF[hb + k];
        a  = fmaf(f, We1[(8   + k) * 128 + j], a);
        bb = fmaf(f, We1[(136 + k) * 128 + j], bb);
    }
    FsP[n * 128 + j] = a * C1;
    FrP[n * 128 + j] = bb * C1;
}

// ---------------------------------------------------------------------------
// laundered B-fragment loader (anchors loads at the call site, defeats LICM)
// ---------------------------------------------------------------------------
__device__ __forceinline__ void loadBz(const short* __restrict__ p,
                                       bf16x8 (&B)[2][4], int w, int lane)
{
    int zz = 0; asm volatile("" : "+v"(zz));
    const bf16x8* p8 = (const bf16x8*)p;
    #pragma unroll
    for (int ctl = 0; ctl < 2; ++ctl)
        #pragma unroll
        for (int kt = 0; kt < 4; ++kt)
            B[ctl][kt] = p8[((w * 2 + ctl) * 4 + kt) * 64 + lane + zz];
}

// MFMA-only part of the 32x128 @ 128x128 layer (weights pre-scaled)
__device__ __forceinline__ void gemm_mfma(const short* sIn_, const bf16x8 (&B)[2][4],
                                          const int (&adrK)[4], f32x4 (&acc)[2][2])
{
    const char* sIn = (const char*)sIn_;
    const f32x4 z = {0.f, 0.f, 0.f, 0.f};
    acc[0][0] = z; acc[0][1] = z; acc[1][0] = z; acc[1][1] = z;
    __builtin_amdgcn_s_setprio(1);
    #pragma unroll
    for (int kt = 0; kt < 4; ++kt) {
        bf16x8 a0 = *(const bf16x8*)(sIn + adrK[kt]);
        bf16x8 a1 = *(const bf16x8*)(sIn + adrK[kt] + 4096);
        acc[0][0] = MFMA16(a0, B[0][kt], acc[0][0], 0, 0, 0);
        acc[0][1] = MFMA16(a0, B[1][kt], acc[0][1], 0, 0, 0);
        acc[1][0] = MFMA16(a1, B[0][kt], acc[1][0], 0, 0, 0);
        acc[1][1] = MFMA16(a1, B[1][kt], acc[1][1], 0, 0, 0);
    }
    __builtin_amdgcn_s_setprio(0);
}

// epilogue: pure silu -> bf16 (cvt_pk) scatter into LDS (optionally keep fp32)
template<bool KEEP>
__device__ __forceinline__ void epi_store(const f32x4 (&acc)[2][2], short* sOut_,
                                          const int (&wAdr)[2][4], f32x4 (&keep)[2][2])
{
    char* sOut = (char*)sOut_;
    #pragma unroll
    for (int rt = 0; rt < 2; ++rt)
        #pragma unroll
        for (int ctl = 0; ctl < 2; ++ctl) {
            float v0 = silu_f(acc[rt][ctl][0]);
            float v1 = silu_f(acc[rt][ctl][1]);
            float v2 = silu_f(acc[rt][ctl][2]);
            float v3 = silu_f(acc[rt][ctl][3]);
            if (KEEP) {
                keep[rt][ctl][0] = v0; keep[rt][ctl][1] = v1;
                keep[rt][ctl][2] = v2; keep[rt][ctl][3] = v3;
            }
            unsigned p01, p23;
            CVT_PK(p01, v0, v1);
            CVT_PK(p23, v2, v3);
            char* o = sOut + rt * 4096;
            *(short*)(o + wAdr[ctl][0]) = (short)(p01 & 0xFFFFu);
            *(short*)(o + wAdr[ctl][1]) = (short)(p01 >> 16);
            *(short*)(o + wAdr[ctl][2]) = (short)(p23 & 0xFFFFu);
            *(short*)(o + wAdr[ctl][3]) = (short)(p23 >> 16);
        }
}

// ---------------------------------------------------------------------------
// k_edge: one block per (sender, half); 8 chunks of 32 receivers.
// R7 structure (7 barriers/chunk, block-shared sLS, LDS e-phase) +
// pre-scaled weights + L1 C-operand + rsq + setprio.
// ---------------------------------------------------------------------------
__global__ __launch_bounds__(256, 4)
void k_edge(const float* __restrict__ pos,
            const float* __restrict__ Winf,
            const float* __restrict__ FsP,
            const float* __restrict__ FrP,
            const short* __restrict__ We1Lp,
            const short* __restrict__ We2p,
            const short* __restrict__ Wx1p,
            const short* __restrict__ Wx2p,
            const short* __restrict__ Wtpp,
            float* __restrict__ MI2,
            float* __restrict__ VEC2)
{
    __shared__ __align__(16) short sX[CH * 128];     // activations ping (swizzled)
    __shared__ __align__(16) short sY[CH * 128];     // activations pong
    __shared__ __align__(16) float sLS[CH * NV * 4]; // (sh.xyz, len), v-slot swizzled
    __shared__ float sWinf[8 * 17];
    __shared__ float sPosS[24];
    __shared__ float sE[CH];
    __shared__ float sVp[4 * 24];

    const int bid = blockIdx.x;
    const int s = bid >> 1, half = bid & 1;
    const int t = threadIdx.x;
    const int lane = t & 63, w = t >> 6;
    const int rl = lane & 15, kg = lane >> 4;

    // ---- per-thread constant LDS byte addresses ----
    const int swz = (rl & 7) << 4;
    const int ktperm = (rl & 4) << 4;
    const int baseRd = rl * 256 + ((kg * 16) ^ (swz & 0x30));
    int adrK[4];
    #pragma unroll
    for (int kt = 0; kt < 4; ++kt) adrK[kt] = baseRd + ((kt * 64) ^ ktperm);
    int wAdr[2][4];
    #pragma unroll
    for (int ctl = 0; ctl < 2; ++ctl)
        #pragma unroll
        for (int jj = 0; jj < 4; ++jj) {
            int r = kg * 4 + jj;
            wAdr[ctl][jj] = r * 256 + ((w * 64 + ctl * 32 + 2 * rl) ^ ((r & 7) << 4));
        }
    const int colg0 = w * 32 + rl, colg1 = colg0 + 16;
    const int er = t >> 3, eo = t & 7;
    const int eAdr0 = er * 256 + ((eo * 32)      ^ ((er & 7) << 4));
    const int eAdr1 = er * 256 + ((eo * 32 + 16) ^ ((er & 7) << 4));
    const int vv = w * 2 + (rl >> 3);

    if (t < 128) sWinf[(t >> 4) * 17 + (t & 15)] = Winf[t];
    if (t < 24)  sPosS[t] = pos[s * 24 + t];

    const float fs0 = FsP[s * 128 + colg0];   // pre-scaled C1
    const float fs1 = FsP[s * 128 + colg1];

    float miacc0 = 0.f, miacc1 = 0.f;
    float vax = 0.f, vay = 0.f, vaz = 0.f;
    __syncthreads();                                              // B0

    for (int c = 0; c < NCHH; ++c) {
        const int r0 = (half * NCHH + c) * CH;

        // ==== chunk-top issue: We2 frags + We1L frags + FrP->C-operand ====
        bf16x8 Bw[2][4];
        loadBz(We2p, Bw, w, lane);
        bf16x8 bL0, bL1;
        {
            int zz = 0; asm volatile("" : "+v"(zz));
            const bf16x8* pL = (const bf16x8*)We1Lp;
            bL0 = pL[(w * 2 + 0) * 64 + lane + zz];
            bL1 = pL[(w * 2 + 1) * 64 + lane + zz];
        }
        f32x4 cIn[2][2];
        {
            int zz = 0; asm volatile("" : "+v"(zz));
            #pragma unroll
            for (int rt = 0; rt < 2; ++rt)
                #pragma unroll
                for (int jj = 0; jj < 4; ++jj) {
                    const float* fp = FrP + (size_t)(r0 + rt * 16 + kg * 4 + jj) * 128 + zz;
                    cIn[rt][0][jj] = fp[colg0] + fs0;   // acc-init = fr' + fs'
                    cIn[rt][1][jj] = fp[colg1] + fs1;
                }
        }

        // ---- ph0: lengths + sh1 -> sLS (block-shared, 1 (r,v) pair/thread) ----
        {
            int r = t >> 3, v = t & 7;
            const float* pr = pos + (size_t)(r0 + r) * 24 + v * 3;
            float dx = sPosS[v * 3 + 0] - pr[0];
            float dy = sPosS[v * 3 + 1] - pr[1];
            float dz = sPosS[v * 3 + 2] - pr[2];
            float sq = fmaxf(dx * dx + dy * dy + dz * dz, 1e-20f);
            float rs = __builtin_amdgcn_rsqf(sq);
            float len = sq * rs;                      // = sqrt(sq); r==s -> sh1=0
            float inv = SQRT3 * rs;
            f32x4 o; o[0] = dx * inv; o[1] = dy * inv; o[2] = dz * inv; o[3] = len;
            *(f32x4*)(sLS + (r * 8 + (v ^ (r & 7))) * 4) = o;
        }
        __syncthreads();                                          // B1

        // ---- L1: lens @ We1L' with C-operand = fr'+fs'; pure-silu epi -> sX ----
        {
            bf16x8 aL0 = {0,0,0,0,0,0,0,0}, aL1 = {0,0,0,0,0,0,0,0};
            if (kg == 0) {
                const float* Lp = sLS + rl * 32;
                const float* Lq = sLS + (rl + 16) * 32;
                unsigned u0[4], u1[4];
                #pragma unroll
                for (int jp = 0; jp < 4; ++jp) {
                    CVT_PK(u0[jp], Lp[((2*jp)   ^ (rl & 7)) * 4 + 3],
                                   Lp[((2*jp+1) ^ (rl & 7)) * 4 + 3]);
                    CVT_PK(u1[jp], Lq[((2*jp)   ^ (rl & 7)) * 4 + 3],
                                   Lq[((2*jp+1) ^ (rl & 7)) * 4 + 3]);
                }
                uint4 v0 = {u0[0], u0[1], u0[2], u0[3]};
                uint4 v1 = {u1[0], u1[1], u1[2], u1[3]};
                aL0 = __builtin_bit_cast(bf16x8, v0);
                aL1 = __builtin_bit_cast(bf16x8, v1);
            }
            f32x4 aP[2][2];
            aP[0][0] = MFMA16(aL0, bL0, cIn[0][0], 0, 0, 0);
            aP[0][1] = MFMA16(aL0, bL1, cIn[0][1], 0, 0, 0);
            aP[1][0] = MFMA16(aL1, bL0, cIn[1][0], 0, 0, 0);
            aP[1][1] = MFMA16(aL1, bL1, cIn[1][1], 0, 0, 0);
            f32x4 dummy[2][2];
            epi_store<false>(aP, sX, wAdr, dummy);
        }
        __syncthreads();                                          // B2

        // ---- L2: m_ij = silu(a1 @ We2') -> sY ; Wx1 issued under epilogue ----
        f32x4 acc[2][2];
        f32x4 keepM[2][2];
        gemm_mfma(sX, Bw, adrK, acc);          // consumes We2 (Bw regs die)
        bf16x8 Bn[2][4];
        loadBz(Wx1p, Bn, w, lane);             // Wx1 in flight: epi + e-phase
        epi_store<true>(acc, sY, wAdr, keepM);
        __syncthreads();                                          // B3

        // ---- e[r] = sigmoid(C2 * m_ij . Winf) ----
        {
            const char* sYc = (const char*)sY;
            uint4 m0 = *(const uint4*)(sYc + eAdr0);
            uint4 m1 = *(const uint4*)(sYc + eAdr1);
            const unsigned mu[8] = {m0.x, m0.y, m0.z, m0.w, m1.x, m1.y, m1.z, m1.w};
            float d = 0.f;
            #pragma unroll
            for (int q = 0; q < 8; ++q) {
                d = fmaf(bflo(mu[q]), sWinf[eo * 17 + 2 * q],     d);
                d = fmaf(bfhi(mu[q]), sWinf[eo * 17 + 2 * q + 1], d);
            }
            d += __shfl_xor(d, 1); d += __shfl_xor(d, 2); d += __shfl_xor(d, 4);
            if (eo == 0) sE[er] = (r0 + er == s) ? 0.f : sigm_f(d * C2);
        }
        __syncthreads();                                          // B4

        // ---- m_i accumulation from registers ----
        #pragma unroll
        for (int rt = 0; rt < 2; ++rt)
            #pragma unroll
            for (int jj = 0; jj < 4; ++jj) {
                float e = sE[rt * 16 + kg * 4 + jj];
                miacc0 = fmaf(keepM[rt][0][jj], e, miacc0);
                miacc1 = fmaf(keepM[rt][1][jj], e, miacc1);
            }

        // ---- L3: phi_x layer 1 ; Wx2 issued under epilogue ----
        gemm_mfma(sY, Bn, adrK, acc);          // consumes Wx1
        loadBz(Wx2p, Bw, w, lane);             // Wx2 in flight: epi + barrier
        epi_store<false>(acc, sX, wAdr, keepM);
        __syncthreads();                                          // B5

        // ---- L4: phi_x layer 2 ; Wtp issued under epilogue ----
        gemm_mfma(sX, Bw, adrK, acc);          // consumes Wx2
        bf16x8 Bt[4];
        {
            int zz = 0; asm volatile("" : "+v"(zz));
            const bf16x8* p8 = (const bf16x8*)Wtpp;
            #pragma unroll
            for (int kt = 0; kt < 4; ++kt) Bt[kt] = p8[(w * 4 + kt) * 64 + lane + zz];
        }
        epi_store<false>(acc, sY, wAdr, keepM);
        __syncthreads();                                          // B6

        // ---- TP gemm (Wtp' includes 1/32) + vec acc from regs ----
        {
            const f32x4 z = {0.f, 0.f, 0.f, 0.f};
            f32x4 acc0 = z, acc1 = z;
            const char* sYc = (const char*)sY;
            __builtin_amdgcn_s_setprio(1);
            #pragma unroll
            for (int kt = 0; kt < 4; ++kt) {
                bf16x8 a0 = *(const bf16x8*)(sYc + adrK[kt]);
                bf16x8 a1 = *(const bf16x8*)(sYc + adrK[kt] + 4096);
                acc0 = MFMA16(a0, Bt[kt], acc0, 0, 0, 0);
                acc1 = MFMA16(a1, Bt[kt], acc1, 0, 0, 0);
            }
            __builtin_amdgcn_s_setprio(0);
            #pragma unroll
            for (int rt = 0; rt < 2; ++rt)
                #pragma unroll
                for (int jj = 0; jj < 4; ++jj) {
                    int row = rt * 16 + kg * 4 + jj;
                    const f32x4 sh = *(const f32x4*)(sLS + (row * 8 + (vv ^ (row & 7))) * 4);
                    float g = rt ? acc1[jj] : acc0[jj];
                    vax = fmaf(g, sh[0], vax);
                    vay = fmaf(g, sh[1], vay);
                    vaz = fmaf(g, sh[2], vaz);
                }
        }
        __syncthreads();                                          // B7
    }

    // ---- epilogue: m_i reduce over row-groups ----
    miacc0 += __shfl_xor(miacc0, 16); miacc0 += __shfl_xor(miacc0, 32);
    miacc1 += __shfl_xor(miacc1, 16); miacc1 += __shfl_xor(miacc1, 32);
    if (lane < 16) {
        float* mo = MI2 + (size_t)(half * NN + s) * 128;
        mo[w * 32 + lane]      = miacc0;
        mo[w * 32 + 16 + lane] = miacc1;
    }
    // ---- vec reduce (1/32 folded into Wtpp) ----
    vax += __shfl_xor(vax, 8);  vay += __shfl_xor(vay, 8);  vaz += __shfl_xor(vaz, 8);
    vax += __shfl_xor(vax, 16); vay += __shfl_xor(vay, 16); vaz += __shfl_xor(vaz, 16);
    vax += __shfl_xor(vax, 32); vay += __shfl_xor(vay, 32); vaz += __shfl_xor(vaz, 32);
    if ((lane & 56) == 0) {
        float* vp = sVp + w * 24 + lane * 3;
        vp[0] = vax; vp[1] = vay; vp[2] = vaz;
    }
    __syncthreads();
    if (t < 24) {
        float sum = sVp[t] + sVp[24 + t] + sVp[48 + t] + sVp[72 + t];
        VEC2[(size_t)(half * NN + s) * 24 + t] = sum;
    }
}

// ---------------------------------------------------------------------------
// k_node: per-node h-MLP + residual + position update (sums the 2 halves).
// ---------------------------------------------------------------------------
__global__ __launch_bounds__(128)
void k_node(const float* __restrict__ pos, const float* __restrict__ feat,
            const float* __restrict__ Wh1, const float* __restrict__ Wh2,
            const float* __restrict__ Wh3,
            const float* __restrict__ MI2, const float* __restrict__ VEC2,
            float* __restrict__ outPos, float* __restrict__ outFeat)
{
    __shared__ float sMi[128], sF[128], sH[128];
    int n = blockIdx.x, j = threadIdx.x;
    sMi[j] = MI2[n * 128 + j] + MI2[NN * 128 + n * 128 + j];
    sF[j]  = feat[n * 128 + j];
    __syncthreads();
    float a = 0.f;
    #pragma unroll 8
    for (int k = 0; k < 128; ++k) a = fmaf(sMi[k], Wh1[k * 128 + j], a);
    #pragma unroll 8
    for (int k = 0; k < 128; ++k) a = fmaf(sF[k], Wh1[(128 + k) * 128 + j], a);
    a = silu_f(a * 0.0625f);            // 1/sqrt(256)
    sH[j] = a;
    __syncthreads();
    float b = 0.f;
    #pragma unroll 8
    for (int k = 0; k < 128; ++k) b = fmaf(sH[k], Wh2[k * 128 + j], b);
    b = silu_f(b * C2);
    sMi[j] = b;
    __syncthreads();
    float cc = 0.f;
    #pragma unroll 8
    for (int k = 0; k < 128; ++k) cc = fmaf(sMi[k], Wh3[k * 128 + j], cc);
    outFeat[n * 128 + j] = cc * C2 + sF[j];
    if (j < 24) outPos[n * 24 + j] = pos[n * 24 + j]
                                   + VEC2[n * 24 + j] + VEC2[NN * 24 + n * 24 + j];
}

// ---------------------------------------------------------------------------
extern "C" void kernel_launch(void* const* d_in, const int* in_sizes, int n_in,
                              void* d_out, int out_size, void* d_ws, size_t ws_size,
                              hipStream_t stream) {
    const float* pos  = (const float*)d_in[0];
    const float* feat = (const float*)d_in[1];
    const float* We1  = (const float*)d_in[2];
    const float* We2  = (const float*)d_in[3];
    const float* Wx1  = (const float*)d_in[4];
    const float* Wx2  = (const float*)d_in[5];
    const float* Winf = (const float*)d_in[6];
    const float* Wtp  = (const float*)d_in[7];
    const float* Wh1  = (const float*)d_in[8];
    const float* Wh2  = (const float*)d_in[9];
    const float* Wh3  = (const float*)d_in[10];

    float* outPos  = (float*)d_out;              // [512*8*3]
    float* outFeat = (float*)d_out + NN * 24;    // [512*128]

    float* ws   = (float*)d_ws;
    float* FsP  = ws;                   // 65536 floats (pre-scaled C1)
    float* FrP  = ws + 65536;           // 65536 (pre-scaled C1)
    float* MI2  = ws + 131072;          // 2*65536
    float* VEC2 = ws + 262144;          // 2*12288
    short* wpack = (short*)(ws + 286720);
    short* We2p  = wpack;               // 16384 shorts (pre-scaled C2)
    short* Wx1p  = wpack + 16384;       // 16384 (C2)
    short* Wx2p  = wpack + 32768;       // 16384 (C2)
    short* Wtpp  = wpack + 49152;       // 8192  (1/32)
    short* We1Lp = wpack + 57344;       // 4096  (C1)

    k_packall<<<dim3(285), dim3(256), 0, stream>>>(We2, Wx1, Wx2, Wtp, We1, feat,
                                                   We2p, Wx1p, Wx2p, Wtpp, We1Lp,
                                                   FsP, FrP);
    k_edge<<<dim3(2 * NN), dim3(256), 0, stream>>>(pos, Winf, FsP, FrP, We1Lp,
                                                   We2p, Wx1p, Wx2p, Wtpp, MI2, VEC2);
    k_node<<<dim3(NN), dim3(128), 0, stream>>>(pos, feat, Wh1, Wh2, Wh3, MI2, VEC2,
                                               outPos, outFeat);
}